// Round 10
// baseline (413.072 us; speedup 1.0000x reference)
//
#include <hip/hip_runtime.h>
#include <stdint.h>

typedef __attribute__((ext_vector_type(8))) short v8s;
typedef __attribute__((ext_vector_type(4))) short v4s;
typedef __attribute__((ext_vector_type(4))) float v4f;

#define MFMA(a, b, c) __builtin_amdgcn_mfma_f32_16x16x32_bf16((a), (b), (c), 0, 0, 0)

__device__ __forceinline__ unsigned short f2bf(float f) {
    unsigned int u = __float_as_uint(f);
    u += 0x7fffu + ((u >> 16) & 1u);           // RNE, inputs are finite
    return (unsigned short)(u >> 16);
}
__device__ __forceinline__ float bf2f(unsigned short h) {
    return __uint_as_float(((unsigned int)h) << 16);
}
// monotone float<->uint key for atomicMax on floats (finite values)
__device__ __forceinline__ unsigned int fkey(float f) {
    unsigned int u = __float_as_uint(f);
    return (u & 0x80000000u) ? ~u : (u | 0x80000000u);
}
__device__ __forceinline__ float kinv(unsigned int k) {
    unsigned int u = (k & 0x80000000u) ? (k & 0x7FFFFFFFu) : ~k;
    return __uint_as_float(u);
}

// async global->LDS, 16B per lane. LDS dest = wave-uniform base (+ lane*16 by HW).
__device__ __forceinline__ void gload16(const void* g, void* l) {
    __builtin_amdgcn_global_load_lds((const __attribute__((address_space(1))) void*)g,
                                     (__attribute__((address_space(3))) void*)l, 16, 0, 0);
}

#define NB 4
#define SEQ 4096
#define ED 1024
#define CAND_CAP 128

// ---- workspace byte offsets (peak ~148 MB, well under proven 224 MB) ----
#define XHI_OFF   (0ll)
#define XLO_OFF   (33554432ll)
#define YHI_OFF   (67108864ll)
#define YLO_OFF   (100663296ll)
#define CNT_OFF   (134217728ll)    // 16384 u32
#define RMX_OFF   (134283264ll)    // 16384 u32
#define LIST_OFF  (134348800ll)    // 16384 x 128 u32 = 8 MB
#define WQH_OFF   (142737408ll)
#define WQL_OFF   (144834560ll)
#define WKH_OFF   (146931712ll)
#define WKL_OFF   (149028864ll)
#define MTH_OFF   (151126016ll)
#define MTL_OFF   (153223168ll)
#define WS_NEED   (155320320ll)

// ============ prep_x: split X -> bf16 hi/lo (pure elementwise) ============
__global__ __launch_bounds__(256) void prep_x(const float* __restrict__ x,
                                              unsigned short* __restrict__ xhi,
                                              unsigned short* __restrict__ xlo) {
    long idx = ((long)blockIdx.x * 256 + threadIdx.x) * 4;
    v4f v = *(const v4f*)(x + idx);
    v4s ph, pl;
#pragma unroll
    for (int e = 0; e < 4; ++e) {
        unsigned short hi = f2bf(v[e]);
        ph[e] = (short)hi;
        pl[e] = (short)f2bf(v[e] - bf2f(hi));
    }
    *(v4s*)(xhi + idx) = ph;
    *(v4s*)(xlo + idx) = pl;
}

// ============ prep_w2: split Wq, Wk (row-major) into bf16 hi/lo ============
__global__ __launch_bounds__(256) void prep_w2(const float* __restrict__ wq,
                                               const float* __restrict__ wk,
                                               unsigned short* __restrict__ wqh,
                                               unsigned short* __restrict__ wql,
                                               unsigned short* __restrict__ wkh,
                                               unsigned short* __restrict__ wkl) {
    const float* w = blockIdx.z ? wk : wq;
    unsigned short* oh = blockIdx.z ? wkh : wqh;
    unsigned short* ol = blockIdx.z ? wkl : wql;
    long idx = ((long)blockIdx.x * 256 + threadIdx.x) * 4;
    v4f v = *(const v4f*)(w + idx);
    v4s ph, pl;
#pragma unroll
    for (int e = 0; e < 4; ++e) {
        unsigned short hi = f2bf(v[e]);
        ph[e] = (short)hi;
        pl[e] = (short)f2bf(v[e] - bf2f(hi));
    }
    *(v4s*)(oh + idx) = ph;
    *(v4s*)(ol + idx) = pl;
}

// ============ init_cand: zero per-row counters and running-max keys ============
__global__ __launch_bounds__(256) void init_cand(unsigned int* __restrict__ cnt,
                                                 unsigned int* __restrict__ rmx) {
    int i = blockIdx.x * 256 + threadIdx.x;   // 16384
    cnt[i] = 0u;
    rmx[i] = 0u;   // kinv(0) is NaN-ish; fmaxf(v, NaN) = v, and all real keys > 0
}

// ============ gemm_m: MT[e'][e] = sum_f Wk[e'][f] * Wq[e][f]  (4-pass split) ============
__global__ __launch_bounds__(256, 2) void gemm_m(const unsigned short* __restrict__ ah,
                                                 const unsigned short* __restrict__ al,
                                                 const unsigned short* __restrict__ bh,
                                                 const unsigned short* __restrict__ bl,
                                                 unsigned short* __restrict__ ch,
                                                 unsigned short* __restrict__ cl) {
    __shared__ __align__(16) unsigned char lds[65536];
    int m0 = blockIdx.x * 128, n0 = blockIdx.y * 128;
    int tid = threadIdx.x, lane = tid & 63, wave = tid >> 6;
    int mo = (wave & 1) * 64, no = (wave >> 1) * 64;
    int lr = lane >> 3;
    int scol = (((lane & 7) ^ lr) << 4);
    v4f vzero = {0.f, 0.f, 0.f, 0.f};
    v4f acc[4][4];
#pragma unroll
    for (int i = 0; i < 4; ++i)
#pragma unroll
        for (int j = 0; j < 4; ++j) acc[i][j] = vzero;
    int cb0 = 16 * (lane >> 4);

    for (int ks = 0; ks < 16; ++ks) {
        __syncthreads();
#pragma unroll
        for (int j = 0; j < 4; ++j) {
            int c = j * 4 + wave;
            int row = c * 8 + lr;
            long ga = ((long)(m0 + row) * ED + ks * 64) * 2 + scol;
            long gb = ((long)(n0 + row) * ED + ks * 64) * 2 + scol;
            unsigned loff = c * 1024;
            gload16((const unsigned char*)ah + ga, lds + loff);
            gload16((const unsigned char*)al + ga, lds + 16384 + loff);
            gload16((const unsigned char*)bh + gb, lds + 32768 + loff);
            gload16((const unsigned char*)bl + gb, lds + 49152 + loff);
        }
        __syncthreads();
#pragma unroll
        for (int kk = 0; kk < 2; ++kk) {
            v8s fah[4], fal[4], fbh[4], fbl[4];
#pragma unroll
            for (int i = 0; i < 4; ++i) {
                int ra = mo + i * 16 + (lane & 15);
                int ca = (kk * 64 + cb0) ^ ((ra & 7) << 4);
                fah[i] = *(const v8s*)(lds +         ra * 128 + ca);
                fal[i] = *(const v8s*)(lds + 16384 + ra * 128 + ca);
                int rb = no + i * 16 + (lane & 15);
                int cbb = (kk * 64 + cb0) ^ ((rb & 7) << 4);
                fbh[i] = *(const v8s*)(lds + 32768 + rb * 128 + cbb);
                fbl[i] = *(const v8s*)(lds + 49152 + rb * 128 + cbb);
            }
#pragma unroll
            for (int i = 0; i < 4; ++i)
#pragma unroll
                for (int j = 0; j < 4; ++j) {
                    acc[i][j] = MFMA(fah[i], fbh[j], acc[i][j]);
                    acc[i][j] = MFMA(fah[i], fbl[j], acc[i][j]);
                    acc[i][j] = MFMA(fal[i], fbh[j], acc[i][j]);
                    acc[i][j] = MFMA(fal[i], fbl[j], acc[i][j]);
                }
        }
    }
#pragma unroll
    for (int i = 0; i < 4; ++i)
#pragma unroll
        for (int j = 0; j < 4; ++j)
#pragma unroll
            for (int r = 0; r < 4; ++r) {
                int row = m0 + mo + i * 16 + (lane >> 4) * 4 + r;
                int col = n0 + no + j * 16 + (lane & 15);
                float v = acc[i][j][r];
                unsigned short hi = f2bf(v);
                long o = (long)row * ED + col;
                ch[o] = hi;
                cl[o] = f2bf(v - bf2f(hi));
            }
}

// ============ gemm_y: Y[16384,1024] = X x M  (A=x hi/lo, B^T=M^T hi/lo, 3 passes) ============
__global__ __launch_bounds__(256, 2) void gemm_y(const unsigned short* __restrict__ ah,
                                                 const unsigned short* __restrict__ al,
                                                 const unsigned short* __restrict__ bh,
                                                 const unsigned short* __restrict__ bl,
                                                 unsigned short* __restrict__ ch,
                                                 unsigned short* __restrict__ cl) {
    __shared__ __align__(16) unsigned char lds[65536];
    int m0 = blockIdx.x * 128, n0 = blockIdx.y * 128;
    int tid = threadIdx.x, lane = tid & 63, wave = tid >> 6;
    int mo = (wave & 1) * 64, no = (wave >> 1) * 64;
    int lr = lane >> 3;
    int scol = (((lane & 7) ^ lr) << 4);
    v4f vzero = {0.f, 0.f, 0.f, 0.f};
    v4f acc[4][4];
#pragma unroll
    for (int i = 0; i < 4; ++i)
#pragma unroll
        for (int j = 0; j < 4; ++j) acc[i][j] = vzero;
    int cb0 = 16 * (lane >> 4);

    for (int ks = 0; ks < 16; ++ks) {
        __syncthreads();
#pragma unroll
        for (int j = 0; j < 4; ++j) {
            int c = j * 4 + wave;
            int row = c * 8 + lr;
            long ga = ((long)(m0 + row) * ED + ks * 64) * 2 + scol;
            long gb = ((long)(n0 + row) * ED + ks * 64) * 2 + scol;
            unsigned loff = c * 1024;
            gload16((const unsigned char*)ah + ga, lds + loff);
            gload16((const unsigned char*)al + ga, lds + 16384 + loff);
            gload16((const unsigned char*)bh + gb, lds + 32768 + loff);
            gload16((const unsigned char*)bl + gb, lds + 49152 + loff);
        }
        __syncthreads();
#pragma unroll
        for (int kk = 0; kk < 2; ++kk) {
            v8s fah[4], fal[4], fbh[4], fbl[4];
#pragma unroll
            for (int i = 0; i < 4; ++i) {
                int ra = mo + i * 16 + (lane & 15);
                int ca = (kk * 64 + cb0) ^ ((ra & 7) << 4);
                fah[i] = *(const v8s*)(lds +         ra * 128 + ca);
                fal[i] = *(const v8s*)(lds + 16384 + ra * 128 + ca);
                int rb = no + i * 16 + (lane & 15);
                int cbb = (kk * 64 + cb0) ^ ((rb & 7) << 4);
                fbh[i] = *(const v8s*)(lds + 32768 + rb * 128 + cbb);
                fbl[i] = *(const v8s*)(lds + 49152 + rb * 128 + cbb);
            }
#pragma unroll
            for (int i = 0; i < 4; ++i)
#pragma unroll
                for (int j = 0; j < 4; ++j) {
                    acc[i][j] = MFMA(fah[i], fbh[j], acc[i][j]);
                    acc[i][j] = MFMA(fah[i], fbl[j], acc[i][j]);
                    acc[i][j] = MFMA(fal[i], fbh[j], acc[i][j]);
                }
        }
    }
#pragma unroll
    for (int i = 0; i < 4; ++i)
#pragma unroll
        for (int j = 0; j < 4; ++j)
#pragma unroll
            for (int r = 0; r < 4; ++r) {
                int row = m0 + mo + i * 16 + (lane >> 4) * 4 + r;
                int col = n0 + no + j * 16 + (lane & 15);
                float v = acc[i][j][r];
                unsigned short hi = f2bf(v);
                long o = (long)row * ED + col;
                ch[o] = hi;
                cl[o] = f2bf(v - bf2f(hi));
            }
}

// ============ gemm_cand: 1-pass S~ tile in regs -> rowmax atomicMax + candidate append ============
// No S~ materialization. z = batch. Threshold uses running global row max (conservative superset).
__global__ __launch_bounds__(256, 4) void gemm_cand(const unsigned short* __restrict__ qh,
                                                    const unsigned short* __restrict__ kh,
                                                    unsigned int* __restrict__ cnt,
                                                    unsigned int* __restrict__ rmx,
                                                    unsigned int* __restrict__ list) {
    __shared__ __align__(16) unsigned char lds[32768];   // Ah | Bh, 16KB each
    int b = blockIdx.z;
    int m0 = blockIdx.x * 128, n0 = blockIdx.y * 128;
    int tid = threadIdx.x, lane = tid & 63, wave = tid >> 6;
    int mo = (wave & 1) * 64, no = (wave >> 1) * 64;
    int lr = lane >> 3;
    int scol = (((lane & 7) ^ lr) << 4);
    v4f vzero = {0.f, 0.f, 0.f, 0.f};
    v4f acc[4][4];
#pragma unroll
    for (int i = 0; i < 4; ++i)
#pragma unroll
        for (int j = 0; j < 4; ++j) acc[i][j] = vzero;
    int cb0 = 16 * (lane >> 4);

    for (int ks = 0; ks < 16; ++ks) {
        __syncthreads();
#pragma unroll
        for (int j = 0; j < 4; ++j) {
            int c = j * 4 + wave;
            int row = c * 8 + lr;
            long ga = ((long)(b * SEQ + m0 + row) * ED + ks * 64) * 2 + scol;
            long gb = ((long)(b * SEQ + n0 + row) * ED + ks * 64) * 2 + scol;
            unsigned loff = c * 1024;
            gload16((const unsigned char*)qh + ga, lds + loff);
            gload16((const unsigned char*)kh + gb, lds + 16384 + loff);
        }
        __syncthreads();
#pragma unroll
        for (int kk = 0; kk < 2; ++kk) {
            v8s fa[4], fb[4];
#pragma unroll
            for (int i = 0; i < 4; ++i) {
                int ra = mo + i * 16 + (lane & 15);
                int ca = (kk * 64 + cb0) ^ ((ra & 7) << 4);
                fa[i] = *(const v8s*)(lds +         ra * 128 + ca);
                int rb = no + i * 16 + (lane & 15);
                int cbb = (kk * 64 + cb0) ^ ((rb & 7) << 4);
                fb[i] = *(const v8s*)(lds + 16384 + rb * 128 + cbb);
            }
#pragma unroll
            for (int i = 0; i < 4; ++i)
#pragma unroll
                for (int j = 0; j < 4; ++j)
                    acc[i][j] = MFMA(fa[i], fb[j], acc[i][j]);
        }
    }

    // ---- epilogue: per-row running max + candidate append (scaled domain) ----
#pragma unroll
    for (int i = 0; i < 4; ++i)
#pragma unroll
        for (int r = 0; r < 4; ++r) {
            float v = fmaxf(fmaxf(acc[i][0][r], acc[i][1][r]),
                            fmaxf(acc[i][2][r], acc[i][3][r])) * 0.03125f;
            v = fmaxf(v, __shfl_xor(v, 1));
            v = fmaxf(v, __shfl_xor(v, 2));
            v = fmaxf(v, __shfl_xor(v, 4));
            v = fmaxf(v, __shfl_xor(v, 8));   // max over the 16-lane col group
            int row = m0 + mo + i * 16 + (lane >> 4) * 4 + r;
            int gr = b * SEQ + row;
            float thr;
            if ((lane & 15) == 0) {
                unsigned int old = atomicMax(&rmx[gr], fkey(v));
                float cur = fmaxf(v, kinv(old));   // fmaxf(v, NaN)=v for init key 0
                thr = cur - 60.0f;
            }
            thr = __shfl(thr, lane & 48);          // broadcast from group leader
#pragma unroll
            for (int j = 0; j < 4; ++j) {
                float sv = acc[i][j][r] * 0.03125f;
                if (sv > thr) {
                    unsigned int idx = atomicAdd(&cnt[gr], 1u);
                    if (idx < CAND_CAP)
                        list[(long)gr * CAND_CAP + idx] = (unsigned int)(n0 + no + j * 16 + (lane & 15));
                }
            }
        }
}

// ============ attn_sparse: exact logits on candidates -> softmax -> sparse PV -> O ============
// 1 wave per row; grid (SEQ/2, NB).
__global__ __launch_bounds__(128) void attn_sparse(const unsigned int* __restrict__ cnt,
                                                   const unsigned int* __restrict__ list,
                                                   const unsigned short* __restrict__ yhi,
                                                   const unsigned short* __restrict__ ylo,
                                                   const float* __restrict__ x,
                                                   float* __restrict__ out) {
    __shared__ float pval[2][CAND_CAP];
    int w = threadIdx.x >> 6, lane = threadIdx.x & 63;
    int b = blockIdx.y;
    int row = blockIdx.x * 2 + w;
    int gr = b * SEQ + row;
    int n = (int)cnt[gr];
    if (n > CAND_CAP) n = CAND_CAP;

    // y row as fp32 (hi+lo), 16 elems/lane
    long ybase = (long)gr * ED;
    int k0 = lane * 16;
    v8s yh0 = *(const v8s*)(yhi + ybase + k0);
    v8s yh1 = *(const v8s*)(yhi + ybase + k0 + 8);
    v8s yl0 = *(const v8s*)(ylo + ybase + k0);
    v8s yl1 = *(const v8s*)(ylo + ybase + k0 + 8);
    float yv[16];
#pragma unroll
    for (int e = 0; e < 8; ++e) {
        yv[e]     = bf2f((unsigned short)yh0[e]) + bf2f((unsigned short)yl0[e]);
        yv[8 + e] = bf2f((unsigned short)yh1[e]) + bf2f((unsigned short)yl1[e]);
    }

    float M = -INFINITY;
    for (int c = 0; c < n; ++c) {
        int col = (int)list[(long)gr * CAND_CAP + c];
        const float* xr = x + ((long)b * SEQ + col) * ED + k0;
        float s = 0.f;
#pragma unroll
        for (int t = 0; t < 4; ++t) {
            v4f xv = *(const v4f*)(xr + t * 4);
#pragma unroll
            for (int e = 0; e < 4; ++e) s += yv[t * 4 + e] * xv[e];
        }
#pragma unroll
        for (int o = 1; o < 64; o <<= 1) s += __shfl_xor(s, o);
        s *= 0.03125f;
        if (lane == 0) pval[w][c] = s;
        M = fmaxf(M, s);
    }

    float sum = 0.f;
    for (int c = 0; c < n; ++c) sum += __expf(pval[w][c] - M);
    float inv = 1.0f / sum;
    v4f a0 = {0.f, 0.f, 0.f, 0.f}, a1 = a0, a2 = a0, a3 = a0;
    for (int c = 0; c < n; ++c) {
        float p = __expf(pval[w][c] - M) * inv;
        int col = (int)list[(long)gr * CAND_CAP + c];
        const float* xr = x + ((long)b * SEQ + col) * ED + k0;
        v4f x0 = *(const v4f*)(xr);
        v4f x1 = *(const v4f*)(xr + 4);
        v4f x2 = *(const v4f*)(xr + 8);
        v4f x3 = *(const v4f*)(xr + 12);
#pragma unroll
        for (int e = 0; e < 4; ++e) {
            a0[e] += p * x0[e];
            a1[e] += p * x1[e];
            a2[e] += p * x2[e];
            a3[e] += p * x3[e];
        }
    }
    float* orow = out + (long)gr * ED + k0;
    *(v4f*)(orow)      = a0;
    *(v4f*)(orow + 4)  = a1;
    *(v4f*)(orow + 8)  = a2;
    *(v4f*)(orow + 12) = a3;
}

extern "C" void kernel_launch(void* const* d_in, const int* in_sizes, int n_in,
                              void* d_out, int out_size, void* d_ws, size_t ws_size,
                              hipStream_t stream) {
    const float* x  = (const float*)d_in[0];
    const float* wq = (const float*)d_in[1];
    const float* wk = (const float*)d_in[2];
    unsigned char* ws = (unsigned char*)d_ws;
    unsigned short* xhi = (unsigned short*)(ws + XHI_OFF);
    unsigned short* xlo = (unsigned short*)(ws + XLO_OFF);
    unsigned short* yhi = (unsigned short*)(ws + YHI_OFF);
    unsigned short* ylo = (unsigned short*)(ws + YLO_OFF);
    unsigned int*   cnt = (unsigned int*)(ws + CNT_OFF);
    unsigned int*   rmx = (unsigned int*)(ws + RMX_OFF);
    unsigned int*   list= (unsigned int*)(ws + LIST_OFF);
    unsigned short* wqh = (unsigned short*)(ws + WQH_OFF);
    unsigned short* wql = (unsigned short*)(ws + WQL_OFF);
    unsigned short* wkh = (unsigned short*)(ws + WKH_OFF);
    unsigned short* wkl = (unsigned short*)(ws + WKL_OFF);
    unsigned short* mth = (unsigned short*)(ws + MTH_OFF);
    unsigned short* mtl = (unsigned short*)(ws + MTL_OFF);

    prep_x<<<16384, 256, 0, stream>>>(x, xhi, xlo);
    prep_w2<<<dim3(1024, 1, 2), 256, 0, stream>>>(wq, wk, wqh, wql, wkh, wkl);
    init_cand<<<64, 256, 0, stream>>>(cnt, rmx);
    gemm_m<<<dim3(8, 8), 256, 0, stream>>>(wkh, wkl, wqh, wql, mth, mtl);
    gemm_y<<<dim3(128, 8), 256, 0, stream>>>(xhi, xlo, mth, mtl, yhi, ylo);
    gemm_cand<<<dim3(32, 32, NB), 256, 0, stream>>>(yhi, xhi, cnt, rmx, list);
    attn_sparse<<<dim3(SEQ / 2, NB), 128, 0, stream>>>(cnt, list, yhi, ylo, x, (float*)d_out);
}

// Round 11
// 348.077 us; speedup vs baseline: 1.1867x; 1.1867x over previous
//
#include <hip/hip_runtime.h>
#include <stdint.h>

typedef __attribute__((ext_vector_type(8))) short v8s;
typedef __attribute__((ext_vector_type(4))) short v4s;
typedef __attribute__((ext_vector_type(4))) float v4f;

#define MFMA(a, b, c) __builtin_amdgcn_mfma_f32_16x16x32_bf16((a), (b), (c), 0, 0, 0)

__device__ __forceinline__ unsigned short f2bf(float f) {
    unsigned int u = __float_as_uint(f);
    u += 0x7fffu + ((u >> 16) & 1u);           // RNE, inputs are finite
    return (unsigned short)(u >> 16);
}
__device__ __forceinline__ float bf2f(unsigned short h) {
    return __uint_as_float(((unsigned int)h) << 16);
}
// monotone float<->uint key for atomicMax on floats (finite values)
__device__ __forceinline__ unsigned int fkey(float f) {
    unsigned int u = __float_as_uint(f);
    return (u & 0x80000000u) ? ~u : (u | 0x80000000u);
}
__device__ __forceinline__ float kinv(unsigned int k) {
    unsigned int u = (k & 0x80000000u) ? (k & 0x7FFFFFFFu) : ~k;
    return __uint_as_float(u);
}

// async global->LDS, 16B per lane. LDS dest = wave-uniform base (+ lane*16 by HW).
__device__ __forceinline__ void gload16(const void* g, void* l) {
    __builtin_amdgcn_global_load_lds((const __attribute__((address_space(1))) void*)g,
                                     (__attribute__((address_space(3))) void*)l, 16, 0, 0);
}

#define NB 4
#define SEQ 4096
#define ED 1024
#define CAND_CAP 256

// ---- workspace byte offsets (peak ~172 MB, under proven 224 MB) ----
#define XHI_OFF   (0ll)
#define XLO_OFF   (33554432ll)
#define YHI_OFF   (67108864ll)
#define YLO_OFF   (100663296ll)
#define CNT_OFF   (134217728ll)    // 16384 u32
#define RMX_OFF   (134283264ll)    // 16384 u32
#define LIST_OFF  (134348800ll)    // 16384 x 256 u64 = 32 MB
#define WQH_OFF   (167903232ll)
#define WQL_OFF   (170000384ll)
#define WKH_OFF   (172097536ll)
#define WKL_OFF   (174194688ll)
#define MTH_OFF   (176291840ll)
#define MTL_OFF   (178388992ll)
#define WS_NEED   (180486144ll)

// ============ prep_x: split X -> bf16 hi/lo (pure elementwise) ============
__global__ __launch_bounds__(256) void prep_x(const float* __restrict__ x,
                                              unsigned short* __restrict__ xhi,
                                              unsigned short* __restrict__ xlo) {
    long idx = ((long)blockIdx.x * 256 + threadIdx.x) * 4;
    v4f v = *(const v4f*)(x + idx);
    v4s ph, pl;
#pragma unroll
    for (int e = 0; e < 4; ++e) {
        unsigned short hi = f2bf(v[e]);
        ph[e] = (short)hi;
        pl[e] = (short)f2bf(v[e] - bf2f(hi));
    }
    *(v4s*)(xhi + idx) = ph;
    *(v4s*)(xlo + idx) = pl;
}

// ============ prep_w2: split Wq, Wk (row-major) into bf16 hi/lo ============
__global__ __launch_bounds__(256) void prep_w2(const float* __restrict__ wq,
                                               const float* __restrict__ wk,
                                               unsigned short* __restrict__ wqh,
                                               unsigned short* __restrict__ wql,
                                               unsigned short* __restrict__ wkh,
                                               unsigned short* __restrict__ wkl) {
    const float* w = blockIdx.z ? wk : wq;
    unsigned short* oh = blockIdx.z ? wkh : wqh;
    unsigned short* ol = blockIdx.z ? wkl : wql;
    long idx = ((long)blockIdx.x * 256 + threadIdx.x) * 4;
    v4f v = *(const v4f*)(w + idx);
    v4s ph, pl;
#pragma unroll
    for (int e = 0; e < 4; ++e) {
        unsigned short hi = f2bf(v[e]);
        ph[e] = (short)hi;
        pl[e] = (short)f2bf(v[e] - bf2f(hi));
    }
    *(v4s*)(oh + idx) = ph;
    *(v4s*)(ol + idx) = pl;
}

// ============ init_cand: zero per-row counters and running-max keys ============
__global__ __launch_bounds__(256) void init_cand(unsigned int* __restrict__ cnt,
                                                 unsigned int* __restrict__ rmx) {
    int i = blockIdx.x * 256 + threadIdx.x;   // 16384
    cnt[i] = 0u;
    rmx[i] = 0u;   // kinv(0) is NaN-ish; fmaxf(v, NaN) = v, and all real keys > 0
}

// ============ gemm_m: MT[e'][e] = sum_f Wk[e'][f] * Wq[e][f]  (4-pass split) ============
__global__ __launch_bounds__(256, 2) void gemm_m(const unsigned short* __restrict__ ah,
                                                 const unsigned short* __restrict__ al,
                                                 const unsigned short* __restrict__ bh,
                                                 const unsigned short* __restrict__ bl,
                                                 unsigned short* __restrict__ ch,
                                                 unsigned short* __restrict__ cl) {
    __shared__ __align__(16) unsigned char lds[65536];
    int m0 = blockIdx.x * 128, n0 = blockIdx.y * 128;
    int tid = threadIdx.x, lane = tid & 63, wave = tid >> 6;
    int mo = (wave & 1) * 64, no = (wave >> 1) * 64;
    int lr = lane >> 3;
    int scol = (((lane & 7) ^ lr) << 4);
    v4f vzero = {0.f, 0.f, 0.f, 0.f};
    v4f acc[4][4];
#pragma unroll
    for (int i = 0; i < 4; ++i)
#pragma unroll
        for (int j = 0; j < 4; ++j) acc[i][j] = vzero;
    int cb0 = 16 * (lane >> 4);

    for (int ks = 0; ks < 16; ++ks) {
        __syncthreads();
#pragma unroll
        for (int j = 0; j < 4; ++j) {
            int c = j * 4 + wave;
            int row = c * 8 + lr;
            long ga = ((long)(m0 + row) * ED + ks * 64) * 2 + scol;
            long gb = ((long)(n0 + row) * ED + ks * 64) * 2 + scol;
            unsigned loff = c * 1024;
            gload16((const unsigned char*)ah + ga, lds + loff);
            gload16((const unsigned char*)al + ga, lds + 16384 + loff);
            gload16((const unsigned char*)bh + gb, lds + 32768 + loff);
            gload16((const unsigned char*)bl + gb, lds + 49152 + loff);
        }
        __syncthreads();
#pragma unroll
        for (int kk = 0; kk < 2; ++kk) {
            v8s fah[4], fal[4], fbh[4], fbl[4];
#pragma unroll
            for (int i = 0; i < 4; ++i) {
                int ra = mo + i * 16 + (lane & 15);
                int ca = (kk * 64 + cb0) ^ ((ra & 7) << 4);
                fah[i] = *(const v8s*)(lds +         ra * 128 + ca);
                fal[i] = *(const v8s*)(lds + 16384 + ra * 128 + ca);
                int rb = no + i * 16 + (lane & 15);
                int cbb = (kk * 64 + cb0) ^ ((rb & 7) << 4);
                fbh[i] = *(const v8s*)(lds + 32768 + rb * 128 + cbb);
                fbl[i] = *(const v8s*)(lds + 49152 + rb * 128 + cbb);
            }
#pragma unroll
            for (int i = 0; i < 4; ++i)
#pragma unroll
                for (int j = 0; j < 4; ++j) {
                    acc[i][j] = MFMA(fah[i], fbh[j], acc[i][j]);
                    acc[i][j] = MFMA(fah[i], fbl[j], acc[i][j]);
                    acc[i][j] = MFMA(fal[i], fbh[j], acc[i][j]);
                    acc[i][j] = MFMA(fal[i], fbl[j], acc[i][j]);
                }
        }
    }
#pragma unroll
    for (int i = 0; i < 4; ++i)
#pragma unroll
        for (int j = 0; j < 4; ++j)
#pragma unroll
            for (int r = 0; r < 4; ++r) {
                int row = m0 + mo + i * 16 + (lane >> 4) * 4 + r;
                int col = n0 + no + j * 16 + (lane & 15);
                float v = acc[i][j][r];
                unsigned short hi = f2bf(v);
                long o = (long)row * ED + col;
                ch[o] = hi;
                cl[o] = f2bf(v - bf2f(hi));
            }
}

// ============ gemm_y: Y[16384,1024] = X x M  (A=x hi/lo, B^T=M^T hi/lo, 3 passes) ============
__global__ __launch_bounds__(256, 2) void gemm_y(const unsigned short* __restrict__ ah,
                                                 const unsigned short* __restrict__ al,
                                                 const unsigned short* __restrict__ bh,
                                                 const unsigned short* __restrict__ bl,
                                                 unsigned short* __restrict__ ch,
                                                 unsigned short* __restrict__ cl) {
    __shared__ __align__(16) unsigned char lds[65536];
    int m0 = blockIdx.x * 128, n0 = blockIdx.y * 128;
    int tid = threadIdx.x, lane = tid & 63, wave = tid >> 6;
    int mo = (wave & 1) * 64, no = (wave >> 1) * 64;
    int lr = lane >> 3;
    int scol = (((lane & 7) ^ lr) << 4);
    v4f vzero = {0.f, 0.f, 0.f, 0.f};
    v4f acc[4][4];
#pragma unroll
    for (int i = 0; i < 4; ++i)
#pragma unroll
        for (int j = 0; j < 4; ++j) acc[i][j] = vzero;
    int cb0 = 16 * (lane >> 4);

    for (int ks = 0; ks < 16; ++ks) {
        __syncthreads();
#pragma unroll
        for (int j = 0; j < 4; ++j) {
            int c = j * 4 + wave;
            int row = c * 8 + lr;
            long ga = ((long)(m0 + row) * ED + ks * 64) * 2 + scol;
            long gb = ((long)(n0 + row) * ED + ks * 64) * 2 + scol;
            unsigned loff = c * 1024;
            gload16((const unsigned char*)ah + ga, lds + loff);
            gload16((const unsigned char*)al + ga, lds + 16384 + loff);
            gload16((const unsigned char*)bh + gb, lds + 32768 + loff);
            gload16((const unsigned char*)bl + gb, lds + 49152 + loff);
        }
        __syncthreads();
#pragma unroll
        for (int kk = 0; kk < 2; ++kk) {
            v8s fah[4], fal[4], fbh[4], fbl[4];
#pragma unroll
            for (int i = 0; i < 4; ++i) {
                int ra = mo + i * 16 + (lane & 15);
                int ca = (kk * 64 + cb0) ^ ((ra & 7) << 4);
                fah[i] = *(const v8s*)(lds +         ra * 128 + ca);
                fal[i] = *(const v8s*)(lds + 16384 + ra * 128 + ca);
                int rb = no + i * 16 + (lane & 15);
                int cbb = (kk * 64 + cb0) ^ ((rb & 7) << 4);
                fbh[i] = *(const v8s*)(lds + 32768 + rb * 128 + cbb);
                fbl[i] = *(const v8s*)(lds + 49152 + rb * 128 + cbb);
            }
#pragma unroll
            for (int i = 0; i < 4; ++i)
#pragma unroll
                for (int j = 0; j < 4; ++j) {
                    acc[i][j] = MFMA(fah[i], fbh[j], acc[i][j]);
                    acc[i][j] = MFMA(fah[i], fbl[j], acc[i][j]);
                    acc[i][j] = MFMA(fal[i], fbh[j], acc[i][j]);
                }
        }
    }
#pragma unroll
    for (int i = 0; i < 4; ++i)
#pragma unroll
        for (int j = 0; j < 4; ++j)
#pragma unroll
            for (int r = 0; r < 4; ++r) {
                int row = m0 + mo + i * 16 + (lane >> 4) * 4 + r;
                int col = n0 + no + j * 16 + (lane & 15);
                float v = acc[i][j][r];
                unsigned short hi = f2bf(v);
                long o = (long)row * ED + col;
                ch[o] = hi;
                cl[o] = f2bf(v - bf2f(hi));
            }
}

// ============ gemm_cand: 1-pass S~ tile in regs -> rowmax atomicMax + candidate append ============
// List entry = (fkey(s~)<<32)|col so the consumer can prune against the global candidate max.
__global__ __launch_bounds__(256, 4) void gemm_cand(const unsigned short* __restrict__ qh,
                                                    const unsigned short* __restrict__ kh,
                                                    unsigned int* __restrict__ cnt,
                                                    unsigned int* __restrict__ rmx,
                                                    unsigned long long* __restrict__ list) {
    __shared__ __align__(16) unsigned char lds[32768];   // Ah | Bh, 16KB each
    int b = blockIdx.z;
    int m0 = blockIdx.x * 128, n0 = blockIdx.y * 128;
    int tid = threadIdx.x, lane = tid & 63, wave = tid >> 6;
    int mo = (wave & 1) * 64, no = (wave >> 1) * 64;
    int lr = lane >> 3;
    int scol = (((lane & 7) ^ lr) << 4);
    v4f vzero = {0.f, 0.f, 0.f, 0.f};
    v4f acc[4][4];
#pragma unroll
    for (int i = 0; i < 4; ++i)
#pragma unroll
        for (int j = 0; j < 4; ++j) acc[i][j] = vzero;
    int cb0 = 16 * (lane >> 4);

    for (int ks = 0; ks < 16; ++ks) {
        __syncthreads();
#pragma unroll
        for (int j = 0; j < 4; ++j) {
            int c = j * 4 + wave;
            int row = c * 8 + lr;
            long ga = ((long)(b * SEQ + m0 + row) * ED + ks * 64) * 2 + scol;
            long gb = ((long)(b * SEQ + n0 + row) * ED + ks * 64) * 2 + scol;
            unsigned loff = c * 1024;
            gload16((const unsigned char*)qh + ga, lds + loff);
            gload16((const unsigned char*)kh + gb, lds + 16384 + loff);
        }
        __syncthreads();
#pragma unroll
        for (int kk = 0; kk < 2; ++kk) {
            v8s fa[4], fb[4];
#pragma unroll
            for (int i = 0; i < 4; ++i) {
                int ra = mo + i * 16 + (lane & 15);
                int ca = (kk * 64 + cb0) ^ ((ra & 7) << 4);
                fa[i] = *(const v8s*)(lds +         ra * 128 + ca);
                int rb = no + i * 16 + (lane & 15);
                int cbb = (kk * 64 + cb0) ^ ((rb & 7) << 4);
                fb[i] = *(const v8s*)(lds + 16384 + rb * 128 + cbb);
            }
#pragma unroll
            for (int i = 0; i < 4; ++i)
#pragma unroll
                for (int j = 0; j < 4; ++j)
                    acc[i][j] = MFMA(fa[i], fb[j], acc[i][j]);
        }
    }

    // ---- epilogue: per-row running max + candidate append (scaled domain) ----
#pragma unroll
    for (int i = 0; i < 4; ++i)
#pragma unroll
        for (int r = 0; r < 4; ++r) {
            float v = fmaxf(fmaxf(acc[i][0][r], acc[i][1][r]),
                            fmaxf(acc[i][2][r], acc[i][3][r])) * 0.03125f;
            v = fmaxf(v, __shfl_xor(v, 1));
            v = fmaxf(v, __shfl_xor(v, 2));
            v = fmaxf(v, __shfl_xor(v, 4));
            v = fmaxf(v, __shfl_xor(v, 8));   // max over the 16-lane col group
            int row = m0 + mo + i * 16 + (lane >> 4) * 4 + r;
            int gr = b * SEQ + row;
            float thr;
            if ((lane & 15) == 0) {
                unsigned int old = atomicMax(&rmx[gr], fkey(v));
                float cur = fmaxf(v, kinv(old));   // fmaxf(v, NaN)=v for init key 0
                thr = cur - 60.0f;
            }
            thr = __shfl(thr, lane & 48);          // broadcast from group leader
#pragma unroll
            for (int j = 0; j < 4; ++j) {
                float sv = acc[i][j][r] * 0.03125f;
                if (sv > thr) {
                    unsigned int idx = atomicAdd(&cnt[gr], 1u);
                    if (idx < CAND_CAP) {
                        unsigned int col = (unsigned int)(n0 + no + j * 16 + (lane & 15));
                        list[(long)gr * CAND_CAP + idx] =
                            ((unsigned long long)fkey(sv) << 32) | col;
                    }
                }
            }
        }
}

// ============ attn_sparse: prune by stored s~, exact logits on survivors, softmax + PV ============
// 1 wave per row; grid (SEQ/2, NB). Survivors: s~ > max_cand(s~) - 60 (superset of needed set).
__global__ __launch_bounds__(128) void attn_sparse(const unsigned int* __restrict__ cnt,
                                                   const unsigned long long* __restrict__ list,
                                                   const unsigned short* __restrict__ yhi,
                                                   const unsigned short* __restrict__ ylo,
                                                   const float* __restrict__ x,
                                                   float* __restrict__ out) {
    __shared__ int scnt[2];
    __shared__ int scol[2][64];
    __shared__ float pval[2][64];
    int w = threadIdx.x >> 6, lane = threadIdx.x & 63;
    int b = blockIdx.y;
    int row = blockIdx.x * 2 + w;
    int gr = b * SEQ + row;
    int n = (int)cnt[gr];
    if (n > CAND_CAP) n = CAND_CAP;
    if (lane == 0) scnt[w] = 0;

    // phase A: max of stored s~ keys over candidates
    const unsigned long long* lrow = list + (long)gr * CAND_CAP;
    unsigned int mk = 0u;
    for (int c = lane; c < n; c += 64) mk = max(mk, (unsigned int)(lrow[c] >> 32));
#pragma unroll
    for (int o = 1; o < 64; o <<= 1) {
        unsigned int other = (unsigned int)__shfl_xor((int)mk, o);
        mk = max(mk, other);
    }
    float thrf = kinv(mk) - 60.0f;

    // phase B: compact survivors
    for (int c = lane; c < n; c += 64) {
        unsigned long long e = lrow[c];
        if (kinv((unsigned int)(e >> 32)) > thrf) {
            int idx = atomicAdd(&scnt[w], 1);
            if (idx < 64) scol[w][idx] = (int)(e & 0xFFFFFFFFu);
        }
    }
    __syncthreads();
    int sn = scnt[w] < 64 ? scnt[w] : 64;

    // phase C: exact fp32 logits for survivors (wave-cooperative dot)
    long ybase = (long)gr * ED;
    int k0 = lane * 16;
    v8s yh0 = *(const v8s*)(yhi + ybase + k0);
    v8s yh1 = *(const v8s*)(yhi + ybase + k0 + 8);
    v8s yl0 = *(const v8s*)(ylo + ybase + k0);
    v8s yl1 = *(const v8s*)(ylo + ybase + k0 + 8);
    float yv[16];
#pragma unroll
    for (int e = 0; e < 8; ++e) {
        yv[e]     = bf2f((unsigned short)yh0[e]) + bf2f((unsigned short)yl0[e]);
        yv[8 + e] = bf2f((unsigned short)yh1[e]) + bf2f((unsigned short)yl1[e]);
    }
    float M = -INFINITY;
    for (int c = 0; c < sn; ++c) {
        const float* xr = x + ((long)b * SEQ + scol[w][c]) * ED + k0;
        float s = 0.f;
#pragma unroll
        for (int t = 0; t < 4; ++t) {
            v4f xv = *(const v4f*)(xr + t * 4);
#pragma unroll
            for (int e = 0; e < 4; ++e) s += yv[t * 4 + e] * xv[e];
        }
#pragma unroll
        for (int o = 1; o < 64; o <<= 1) s += __shfl_xor(s, o);
        s *= 0.03125f;
        if (lane == 0) pval[w][c] = s;
        M = fmaxf(M, s);
    }

    // phase D: softmax weights + sparse PV
    float sum = 0.f;
    for (int c = 0; c < sn; ++c) sum += __expf(pval[w][c] - M);
    float inv = 1.0f / sum;
    v4f a0 = {0.f, 0.f, 0.f, 0.f}, a1 = a0, a2 = a0, a3 = a0;
    for (int c = 0; c < sn; ++c) {
        float p = __expf(pval[w][c] - M) * inv;
        const float* xr = x + ((long)b * SEQ + scol[w][c]) * ED + k0;
        v4f x0 = *(const v4f*)(xr);
        v4f x1 = *(const v4f*)(xr + 4);
        v4f x2 = *(const v4f*)(xr + 8);
        v4f x3 = *(const v4f*)(xr + 12);
#pragma unroll
        for (int e = 0; e < 4; ++e) {
            a0[e] += p * x0[e];
            a1[e] += p * x1[e];
            a2[e] += p * x2[e];
            a3[e] += p * x3[e];
        }
    }
    float* orow = out + (long)gr * ED + k0;
    *(v4f*)(orow)      = a0;
    *(v4f*)(orow + 4)  = a1;
    *(v4f*)(orow + 8)  = a2;
    *(v4f*)(orow + 12) = a3;
}

extern "C" void kernel_launch(void* const* d_in, const int* in_sizes, int n_in,
                              void* d_out, int out_size, void* d_ws, size_t ws_size,
                              hipStream_t stream) {
    const float* x  = (const float*)d_in[0];
    const float* wq = (const float*)d_in[1];
    const float* wk = (const float*)d_in[2];
    unsigned char* ws = (unsigned char*)d_ws;
    unsigned short* xhi = (unsigned short*)(ws + XHI_OFF);
    unsigned short* xlo = (unsigned short*)(ws + XLO_OFF);
    unsigned short* yhi = (unsigned short*)(ws + YHI_OFF);
    unsigned short* ylo = (unsigned short*)(ws + YLO_OFF);
    unsigned int*   cnt = (unsigned int*)(ws + CNT_OFF);
    unsigned int*   rmx = (unsigned int*)(ws + RMX_OFF);
    unsigned long long* list = (unsigned long long*)(ws + LIST_OFF);
    unsigned short* wqh = (unsigned short*)(ws + WQH_OFF);
    unsigned short* wql = (unsigned short*)(ws + WQL_OFF);
    unsigned short* wkh = (unsigned short*)(ws + WKH_OFF);
    unsigned short* wkl = (unsigned short*)(ws + WKL_OFF);
    unsigned short* mth = (unsigned short*)(ws + MTH_OFF);
    unsigned short* mtl = (unsigned short*)(ws + MTL_OFF);

    prep_x<<<16384, 256, 0, stream>>>(x, xhi, xlo);
    prep_w2<<<dim3(1024, 1, 2), 256, 0, stream>>>(wq, wk, wqh, wql, wkh, wkl);
    init_cand<<<64, 256, 0, stream>>>(cnt, rmx);
    gemm_m<<<dim3(8, 8), 256, 0, stream>>>(wkh, wkl, wqh, wql, mth, mtl);
    gemm_y<<<dim3(128, 8), 256, 0, stream>>>(xhi, xlo, mth, mtl, yhi, ylo);
    gemm_cand<<<dim3(32, 32, NB), 256, 0, stream>>>(yhi, xhi, cnt, rmx, list);
    attn_sparse<<<dim3(SEQ / 2, NB), 128, 0, stream>>>(cnt, list, yhi, ylo, x, (float*)d_out);
}